// Round 1
// baseline (4586.849 us; speedup 1.0000x reference)
//
#include <hip/hip_runtime.h>
#include <hip/hip_bf16.h>

// Problem constants (match reference)
#define BB 4
#define TT 1024
#define DM 1024
#define HH 16
#define DK 64
#define DV 64
#define POS_NUM 2047

// ---------------------------------------------------------------------------
// Kernel 1: QKV projection.
// Q[b,h,t,e] = sum_d x[b,t,h*64+d] * W_Q[h,d,e]   (same for K,V)
// grid: (T/64, B*H), block 256.
// ---------------------------------------------------------------------------
__global__ __launch_bounds__(256) void qkv_kernel(
    const float* __restrict__ x,
    const float* __restrict__ WQ,
    const float* __restrict__ WK,
    const float* __restrict__ WV,
    float* __restrict__ Qg,
    float* __restrict__ Kg,
    float* __restrict__ Vg) {
  __shared__ float wq[64][64];
  __shared__ float wk[64][64];
  __shared__ float wv[64][64];
  __shared__ float xs[4][64];

  const int bh = blockIdx.y;
  const int b = bh >> 4, h = bh & 15;
  const int t0 = blockIdx.x * 64;
  const int tid = threadIdx.x;

  for (int i = tid; i < 4096; i += 256) {
    const int d = i >> 6, e = i & 63;
    wq[d][e] = WQ[h * 4096 + i];
    wk[d][e] = WK[h * 4096 + i];
    wv[d][e] = WV[h * 4096 + i];
  }
  __syncthreads();

  const int tt = tid >> 6, e = tid & 63;
  for (int it = 0; it < 16; ++it) {
    const int t = t0 + it * 4 + tt;
    xs[tt][e] = x[((size_t)b * TT + t) * DM + h * 64 + e];
    __syncthreads();
    float aq = 0.f, ak = 0.f, av = 0.f;
#pragma unroll
    for (int d = 0; d < 64; ++d) {
      const float xv = xs[tt][d];
      aq += xv * wq[d][e];
      ak += xv * wk[d][e];
      av += xv * wv[d][e];
    }
    const size_t o = ((size_t)bh * TT + t) * 64 + e;
    Qg[o] = aq;
    Kg[o] = ak;
    Vg[o] = av;
    __syncthreads();
  }
}

// ---------------------------------------------------------------------------
// Kernel 2: fused attention for one (b,h,q) row per block.
// scores[k] = (Q[q]·(K[k]+posK[pos[q,k]]) + mask[q,k]) / 8
// attn = softmax(scores); ctx[d] = sum_k attn[k]*(V[k,d]+posV[pos[q,k],d])
// ctx written in [B,T,H*DV] layout for the output GEMM.
// grid: (T, B*H), block 256, dynamic LDS.
// ---------------------------------------------------------------------------
__global__ __launch_bounds__(256) void attn_kernel(
    const float* __restrict__ Qg,
    const float* __restrict__ Kg,
    const float* __restrict__ Vg,
    const float* __restrict__ posK,
    const float* __restrict__ posV,
    const float* __restrict__ maskp,
    const int* __restrict__ pos,
    float* __restrict__ ctx) {
  extern __shared__ float smem[];
  float* kp = smem;                    // 256*65 = 16640
  float* attn_sh = kp + 256 * 65;      // 1024
  float* q_sh = attn_sh + 1024;        // 64
  float* wred = q_sh + 64;             // 8
  float* cred = wred + 8;              // 256
  int* pos_sh = (int*)(cred + 256);    // 1024

  const int q = blockIdx.x;
  const int bh = blockIdx.y;
  const int tid = threadIdx.x;
  const int lane = tid & 63, wid = tid >> 6;

  for (int i = tid; i < TT; i += 256) pos_sh[i] = pos[(size_t)q * TT + i];
  if (tid < 64) q_sh[tid] = Qg[((size_t)bh * TT + q) * DK + tid];
  __syncthreads();

  float s_reg[4];
  float m = -1e30f;
  const float* Kb = Kg + (size_t)bh * TT * DK;

  for (int tile = 0; tile < 4; ++tile) {
    const int k0 = tile * 256;
    // stage (K + PK) tile: 256 rows x 64
#pragma unroll
    for (int sub = 0; sub < 4; ++sub) {
      const int r = sub * 64 + (tid >> 2);
      const int c = (tid & 3) * 16;
      const float* Krow = Kb + (size_t)(k0 + r) * DK;
      const float* Prow = posK + (size_t)pos_sh[k0 + r] * DK;
#pragma unroll
      for (int j = 0; j < 16; ++j)
        kp[r * 65 + c + j] = Krow[c + j] + Prow[c + j];
    }
    __syncthreads();
    float s = 0.f;
#pragma unroll
    for (int d = 0; d < 64; ++d) s += q_sh[d] * kp[tid * 65 + d];
    s = (s + maskp[(size_t)q * TT + k0 + tid]) * 0.125f;
    s_reg[tile] = s;
    m = fmaxf(m, s);
    __syncthreads();  // before kp overwrite
  }

  // block-wide max
#pragma unroll
  for (int off = 32; off; off >>= 1) m = fmaxf(m, __shfl_xor(m, off));
  if (lane == 0) wred[wid] = m;
  __syncthreads();
  m = fmaxf(fmaxf(wred[0], wred[1]), fmaxf(wred[2], wred[3]));

  float lsum = 0.f;
#pragma unroll
  for (int tile = 0; tile < 4; ++tile) {
    const float p = __expf(s_reg[tile] - m);
    attn_sh[tile * 256 + tid] = p;
    lsum += p;
  }
#pragma unroll
  for (int off = 32; off; off >>= 1) lsum += __shfl_xor(lsum, off);
  __syncthreads();  // wred[0..3] reads done; attn_sh visible
  if (lane == 0) wred[4 + wid] = lsum;
  __syncthreads();
  const float inv_l = 1.0f / (wred[4] + wred[5] + wred[6] + wred[7]);

  // ctx pass: 4 groups of 64 lanes, group g handles k = g, g+4, ...
  const int g = tid >> 6, d = tid & 63;
  const float* Vb = Vg + (size_t)bh * TT * DV;
  float acc = 0.f;
#pragma unroll 4
  for (int k = g; k < TT; k += 4) {
    const float a = attn_sh[k];
    const float v = Vb[(size_t)k * DV + d];
    const float pv = posV[(size_t)pos_sh[k] * DV + d];
    acc += a * (v + pv);
  }
  cred[g * 64 + d] = acc;
  __syncthreads();
  if (tid < 64) {
    const float c0 =
        (cred[tid] + cred[64 + tid] + cred[128 + tid] + cred[192 + tid]) * inv_l;
    const int b = bh >> 4, h = bh & 15;
    ctx[((size_t)b * TT + q) * (HH * DV) + h * DV + tid] = c0;
  }
}

// ---------------------------------------------------------------------------
// Kernel 3: output projection. C[4096,1024] = A[4096,1024] @ Wz[1024,1024]
// Classic 64x64 tile, BK=16, 256 threads, 4x4 per thread.
// grid: (1024/64, 4096/64) = (16, 64)
// ---------------------------------------------------------------------------
__global__ __launch_bounds__(256) void outproj_kernel(
    const float* __restrict__ A,
    const float* __restrict__ Wz,
    float* __restrict__ C) {
  __shared__ float As[16][64];  // [k][m]
  __shared__ float Bs[16][64];  // [k][n]
  const int n0 = blockIdx.x * 64;
  const int m0 = blockIdx.y * 64;
  const int tid = threadIdx.x;
  const int tm = tid >> 4, tn = tid & 15;

  float acc[4][4] = {};

  for (int k0 = 0; k0 < 1024; k0 += 16) {
    {
      const int r = tid >> 2, c = (tid & 3) * 4;
      const float4 av = *(const float4*)(A + (size_t)(m0 + r) * 1024 + k0 + c);
      As[c + 0][r] = av.x;
      As[c + 1][r] = av.y;
      As[c + 2][r] = av.z;
      As[c + 3][r] = av.w;
      const int br = tid >> 4, bc = (tid & 15) * 4;
      *(float4*)&Bs[br][bc] =
          *(const float4*)(Wz + (size_t)(k0 + br) * 1024 + n0 + bc);
    }
    __syncthreads();
#pragma unroll
    for (int k = 0; k < 16; ++k) {
      float a[4], bv[4];
      *(float4*)a = *(const float4*)&As[k][tm * 4];
      *(float4*)bv = *(const float4*)&Bs[k][tn * 4];
#pragma unroll
      for (int i = 0; i < 4; ++i)
#pragma unroll
        for (int j = 0; j < 4; ++j) acc[i][j] += a[i] * bv[j];
    }
    __syncthreads();
  }
#pragma unroll
  for (int i = 0; i < 4; ++i) {
    const size_t row = (size_t)(m0 + tm * 4 + i) * 1024 + n0 + tn * 4;
#pragma unroll
    for (int j = 0; j < 4; ++j) C[row + j] = acc[i][j];
  }
}

// ---------------------------------------------------------------------------
extern "C" void kernel_launch(void* const* d_in, const int* in_sizes, int n_in,
                              void* d_out, int out_size, void* d_ws,
                              size_t ws_size, hipStream_t stream) {
  const float* x = (const float*)d_in[0];
  const float* WQ = (const float*)d_in[1];
  const float* WK = (const float*)d_in[2];
  const float* WV = (const float*)d_in[3];
  const float* WZ = (const float*)d_in[4];
  const float* posK = (const float*)d_in[5];
  const float* posV = (const float*)d_in[6];
  const float* maskp = (const float*)d_in[7];
  const int* pos = (const int*)d_in[8];
  float* out = (float*)d_out;

  // workspace layout (floats): Q,K,V [B,H,T,64] each 4194304; ctx [B,T,1024]
  float* Q = (float*)d_ws;
  float* K = Q + (size_t)BB * HH * TT * DK;
  float* V = K + (size_t)BB * HH * TT * DK;
  float* ctx = V + (size_t)BB * HH * TT * DV;

  qkv_kernel<<<dim3(TT / 64, BB * HH), 256, 0, stream>>>(x, WQ, WK, WV, Q, K, V);

  const size_t sh_bytes = (256 * 65 + 1024 + 64 + 8 + 256 + 1024) * 4;
  attn_kernel<<<dim3(TT, BB * HH), 256, sh_bytes, stream>>>(
      Q, K, V, posK, posV, maskp, pos, ctx);

  outproj_kernel<<<dim3(1024 / 64, 4096 / 64), 256, 0, stream>>>(ctx, WZ, out);
}

// Round 3
// 640.934 us; speedup vs baseline: 7.1565x; 7.1565x over previous
//
#include <hip/hip_runtime.h>
#include <hip/hip_bf16.h>

#define BB 4
#define TT 1024
#define DM 1024
#define HH 16

typedef __attribute__((ext_vector_type(8))) short short8;
typedef __attribute__((ext_vector_type(4))) short short4v;
typedef __attribute__((ext_vector_type(4))) float f32x4;
typedef __hip_bfloat16 bf16;

__device__ __forceinline__ f32x4 mfma16(short8 a, short8 b, f32x4 c) {
  return __builtin_amdgcn_mfma_f32_16x16x32_bf16(a, b, c, 0, 0, 0);
}

// ---------------------------------------------------------------------------
// prep: posK fp32 [2047][64] -> bf16 [2048][64] (row 2047 zeroed)
// ---------------------------------------------------------------------------
__global__ __launch_bounds__(256) void prep_posk_kernel(
    const float* __restrict__ posK, bf16* __restrict__ posKbf) {
  const int idx = blockIdx.x * 256 + threadIdx.x;   // 0 .. 2048*64-1
  const int p = idx >> 6, d = idx & 63;
  const float v = (p < 2047) ? posK[(size_t)p * 64 + d] : 0.f;
  posKbf[idx] = __float2bfloat16(v);
}

// ---------------------------------------------------------------------------
// prep: WzT bf16 [n][k] = Wz fp32 [k][n]
// ---------------------------------------------------------------------------
__global__ __launch_bounds__(256) void trans_wz_kernel(
    const float* __restrict__ Wz, bf16* __restrict__ WzT) {
  __shared__ bf16 tile[64][72];
  const int k0 = blockIdx.y * 64, n0 = blockIdx.x * 64;
  const int tid = threadIdx.x;
  const int r = tid >> 2, c = (tid & 3) * 16;
  const float* s = Wz + (size_t)(k0 + r) * 1024 + n0 + c;
#pragma unroll
  for (int i = 0; i < 16; ++i) tile[r][c + i] = __float2bfloat16(s[i]);
  __syncthreads();
  const int n = tid >> 2;
  bf16* o = WzT + (size_t)(n0 + n) * 1024 + k0 + c;
#pragma unroll
  for (int i = 0; i < 16; ++i) o[i] = tile[c + i][n];
}

// ---------------------------------------------------------------------------
// transpose V: [bh][1024][64] bf16 -> Vt [bh][64][1024] bf16
// ---------------------------------------------------------------------------
__global__ __launch_bounds__(256) void trans_v_kernel(
    const bf16* __restrict__ src, bf16* __restrict__ dst) {
  __shared__ bf16 tile[64][72];
  const int bh = blockIdx.y, t0 = blockIdx.x * 64;
  const int tid = threadIdx.x;
  const int r = tid >> 2, c = (tid & 3) * 16;
  const bf16* s = src + ((size_t)bh * TT + t0 + r) * 64 + c;
  *(short8*)(&tile[r][c]) = *(const short8*)(s);
  *(short8*)(&tile[r][c + 8]) = *(const short8*)(s + 8);
  __syncthreads();
  const int d = tid >> 2;
  bf16* o = dst + ((size_t)bh * 64 + d) * TT + t0 + c;
#pragma unroll
  for (int i = 0; i < 16; ++i) o[i] = tile[c + i][d];
}

// ---------------------------------------------------------------------------
// QKV projection -> bf16. grid (16, 64bh), block 256
// ---------------------------------------------------------------------------
__global__ __launch_bounds__(256) void qkv_kernel(
    const float* __restrict__ x,
    const float* __restrict__ WQ,
    const float* __restrict__ WK,
    const float* __restrict__ WV,
    bf16* __restrict__ Qg, bf16* __restrict__ Kg, bf16* __restrict__ Vg) {
  __shared__ float wq[64][64];
  __shared__ float wk[64][64];
  __shared__ float wv[64][64];
  __shared__ float xs[4][64];

  const int bh = blockIdx.y;
  const int b = bh >> 4, h = bh & 15;
  const int t0 = blockIdx.x * 64;
  const int tid = threadIdx.x;

  for (int i = tid; i < 4096; i += 256) {
    const int d = i >> 6, e = i & 63;
    wq[d][e] = WQ[h * 4096 + i];
    wk[d][e] = WK[h * 4096 + i];
    wv[d][e] = WV[h * 4096 + i];
  }
  __syncthreads();

  const int tt = tid >> 6, e = tid & 63;
  for (int it = 0; it < 16; ++it) {
    const int t = t0 + it * 4 + tt;
    xs[tt][e] = x[((size_t)b * TT + t) * DM + h * 64 + e];
    __syncthreads();
    float aq = 0.f, ak = 0.f, av = 0.f;
#pragma unroll
    for (int d = 0; d < 64; ++d) {
      const float xv = xs[tt][d];
      aq += xv * wq[d][e];
      ak += xv * wk[d][e];
      av += xv * wv[d][e];
    }
    const size_t o = ((size_t)bh * TT + t) * 64 + e;
    Qg[o] = __float2bfloat16(aq);
    Kg[o] = __float2bfloat16(ak);
    Vg[o] = __float2bfloat16(av);
    __syncthreads();
  }
}

// ---------------------------------------------------------------------------
// Fused score kernel: per (bh, 16-q tile):
//   QP[16][2048] = Q @ posK^T (MFMA, bf16 in LDS)
//   loop k-tiles(64): S = Q@K^T (MFMA, wave w -> k-slice w*16) + QP[pos]+mask,
//     /8; P=exp(S); store P to Pws; wave w accumulates PV for d-tile w*16.
// grid (16 qtiles, 64 bh) per slab of 256 q. block 256 (4 waves).
// ---------------------------------------------------------------------------
#define QP_S 2052
#define KSH_S 72
#define PSM_S 72
#define POS_S 66

__global__ __launch_bounds__(256, 2) void score_pv_kernel(
    const bf16* __restrict__ Qb,
    const bf16* __restrict__ Kb,
    const bf16* __restrict__ posKbf,
    const bf16* __restrict__ Vt,
    const float* __restrict__ maskp,
    const int* __restrict__ pos,
    bf16* __restrict__ Pws,        // [256 qlocal][64 bh][1024 k]
    float* __restrict__ l_ws,      // [64 bh][1024 q]
    float* __restrict__ ctxU,      // [b][t][1024] fp32 unnormalized
    int slab) {
  __shared__ __align__(16) bf16 QPsh[16 * QP_S];
  __shared__ __align__(16) bf16 Ksh[64 * KSH_S];
  __shared__ __align__(16) bf16 Psm[16 * PSM_S];
  __shared__ unsigned short possh[16 * POS_S];
  __shared__ float lred[4][16];

  const int bh = blockIdx.y;
  const int qt = blockIdx.x;
  const int qlocal0 = qt * 16;
  const int qg0 = slab * 256 + qlocal0;
  const int tid = threadIdx.x;
  const int w = tid >> 6;
  const int lane = tid & 63;
  const int l15 = lane & 15;
  const int hi = lane >> 4;

  // A-frags: Q rows (row = l15, k-chunk = hi*8, second frag +32)
  const bf16* Qrow = Qb + ((size_t)bh * TT + qg0 + l15) * 64 + hi * 8;
  const short8 aq0 = *(const short8*)(Qrow);
  const short8 aq1 = *(const short8*)(Qrow + 32);

  // ---- QP phase: wave w covers p-tiles w*32 .. w*32+31 (16 p each)
  for (int i = 0; i < 32; ++i) {
    const int pt = w * 32 + i;
    const bf16* Kp = posKbf + ((size_t)(pt * 16 + l15)) * 64 + hi * 8;
    const short8 b0 = *(const short8*)(Kp);
    const short8 b1 = *(const short8*)(Kp + 32);
    f32x4 acc = {0.f, 0.f, 0.f, 0.f};
    acc = mfma16(aq0, b0, acc);
    acc = mfma16(aq1, b1, acc);
#pragma unroll
    for (int j = 0; j < 4; ++j)
      QPsh[(hi * 4 + j) * QP_S + pt * 16 + l15] = __float2bfloat16(acc[j]);
  }
  __syncthreads();

  // wave w owns PV output d-tile [w*16, w*16+16)
  f32x4 acc_pv = {0.f, 0.f, 0.f, 0.f};
  float lp[4] = {0.f, 0.f, 0.f, 0.f};
  const bf16* Kbh = Kb + (size_t)bh * TT * 64;
  const bf16* Vtbh = Vt + (size_t)bh * 64 * TT;

  for (int it = 0; it < 16; ++it) {
    const int k0 = it * 64;
    // stage K tile [64][64] -> Ksh, pos tile [16][64] -> possh
    {
      const int r = tid >> 2, c = (tid & 3) * 16;
      const bf16* src = Kbh + (size_t)(k0 + r) * 64 + c;
      *(short8*)(Ksh + r * KSH_S + c) = *(const short8*)(src);
      *(short8*)(Ksh + r * KSH_S + c + 8) = *(const short8*)(src + 8);
      const int pr = tid >> 4, pc = (tid & 15) * 4;
      const int* ps = pos + (size_t)(qg0 + pr) * TT + k0 + pc;
      possh[pr * POS_S + pc + 0] = (unsigned short)ps[0];
      possh[pr * POS_S + pc + 1] = (unsigned short)ps[1];
      possh[pr * POS_S + pc + 2] = (unsigned short)ps[2];
      possh[pr * POS_S + pc + 3] = (unsigned short)ps[3];
    }
    __syncthreads();
    // content scores: wave's 16-k slice
    const bf16* krow = Ksh + (w * 16 + l15) * KSH_S + hi * 8;
    const short8 b0 = *(const short8*)(krow);
    const short8 b1 = *(const short8*)(krow + 32);
    f32x4 s = {0.f, 0.f, 0.f, 0.f};
    s = mfma16(aq0, b0, s);
    s = mfma16(aq1, b1, s);
    // + QP gather + mask, *0.125, exp -> Psm
    const int kk = w * 16 + l15;
#pragma unroll
    for (int j = 0; j < 4; ++j) {
      const int q = hi * 4 + j;
      const int p = possh[q * POS_S + kk];
      float sv = s[j] + __bfloat162float(QPsh[q * QP_S + p]);
      sv = (sv + maskp[(size_t)(qg0 + q) * TT + k0 + kk]) * 0.125f;
      const float pe = __expf(sv);
      lp[j] += pe;
      Psm[q * PSM_S + kk] = __float2bfloat16(pe);
    }
    __syncthreads();
    // store P tile to global (unnormalized)
    {
      const int r = tid >> 4, c = (tid & 15) * 4;
      *(short4v*)(Pws + ((size_t)(qlocal0 + r) * 64 + bh) * TT + k0 + c) =
          *(const short4v*)(Psm + r * PSM_S + c);
    }
    // PV MFMAs: wave w does d-tile nt=w only:
    // ctx[q][w*16+n] += P[q][k] * Vt[w*16+n][k0+k], k over 64
#pragma unroll
    for (int kc = 0; kc < 2; ++kc) {
      const short8 pa = *(const short8*)(Psm + l15 * PSM_S + kc * 32 + hi * 8);
      const short8 bv = *(const short8*)(
          Vtbh + (size_t)(w * 16 + l15) * TT + k0 + kc * 32 + hi * 8);
      acc_pv = mfma16(pa, bv, acc_pv);
    }
    __syncthreads();
  }

  // l row-sums: waves hold disjoint k-slices -> sum across lanes then waves
#pragma unroll
  for (int j = 0; j < 4; ++j) {
    float v = lp[j];
    v += __shfl_xor(v, 1);
    v += __shfl_xor(v, 2);
    v += __shfl_xor(v, 4);
    v += __shfl_xor(v, 8);
    if (l15 == 0) lred[w][hi * 4 + j] = v;
  }
  __syncthreads();
  if (tid < 16) {
    const float l = lred[0][tid] + lred[1][tid] + lred[2][tid] + lred[3][tid];
    l_ws[(size_t)bh * TT + qg0 + tid] = l;
  }
  // ctxU scatter: wave w owns d-range [w*16, w*16+16); rows q = hi*4+j
  {
    const int b = bh >> 4, h = bh & 15;
#pragma unroll
    for (int j = 0; j < 4; ++j) {
      const int q = hi * 4 + j;
      ctxU[((size_t)b * TT + qg0 + q) * DM + h * 64 + w * 16 + l15] = acc_pv[j];
    }
  }
}

// ---------------------------------------------------------------------------
// PV gather kernel: one block per q (all 64 bh). grid 256 per slab, block 512.
// ctx[b][t][h*64+d] = (ctxU + sum_k P[q][bh][k]*posV[pos[q][k]][d]) / l
// ---------------------------------------------------------------------------
__global__ __launch_bounds__(512) void pv_gather_kernel(
    const bf16* __restrict__ Pws,
    const float* __restrict__ posV,
    const int* __restrict__ pos,
    const float* __restrict__ l_ws,
    const float* __restrict__ ctxU,
    bf16* __restrict__ ctxB,
    int slab) {
  __shared__ __align__(16) float PVsh[64 * 64];
  __shared__ __align__(16) bf16 Psh[64 * 72];
  __shared__ unsigned short possh2[1024];

  const int qlocal = blockIdx.x;
  const int q = slab * 256 + qlocal;
  const int tid = threadIdx.x;
  const int bhm = tid >> 3;  // 0..63
  const int dg = tid & 7;    // 0..7

  for (int i = tid; i < 1024; i += 512)
    possh2[i] = (unsigned short)pos[(size_t)q * TT + i];
  __syncthreads();

  f32x4 acc0 = {0.f, 0.f, 0.f, 0.f};
  f32x4 acc1 = {0.f, 0.f, 0.f, 0.f};

  for (int it = 0; it < 16; ++it) {
    const int k0 = it * 64;
    {
      const int r = tid >> 3;
      const int p = possh2[k0 + r];
      const float* src = posV + (size_t)p * 64 + dg * 8;
      *(f32x4*)(PVsh + r * 64 + dg * 8) = *(const f32x4*)(src);
      *(f32x4*)(PVsh + r * 64 + dg * 8 + 4) = *(const f32x4*)(src + 4);
      const bf16* psrc = Pws + ((size_t)qlocal * 64 + r) * TT + k0 + dg * 8;
      *(short8*)(Psh + r * 72 + dg * 8) = *(const short8*)(psrc);
    }
    __syncthreads();
#pragma unroll 4
    for (int k = 0; k < 64; ++k) {
      const float pa = __bfloat162float(Psh[bhm * 72 + k]);
      const f32x4 v0 = *(const f32x4*)(PVsh + k * 64 + dg * 8);
      const f32x4 v1 = *(const f32x4*)(PVsh + k * 64 + dg * 8 + 4);
      acc0 += pa * v0;
      acc1 += pa * v1;
    }
    __syncthreads();
  }

  const int b = bhm >> 4, h = bhm & 15;
  const float invl = 1.0f / l_ws[(size_t)bhm * TT + q];
  const float* cu = ctxU + ((size_t)b * TT + q) * DM + h * 64 + dg * 8;
  bf16* co = ctxB + ((size_t)b * TT + q) * DM + h * 64 + dg * 8;
#pragma unroll
  for (int j = 0; j < 4; ++j) {
    co[j] = __float2bfloat16((cu[j] + acc0[j]) * invl);
    co[j + 4] = __float2bfloat16((cu[j + 4] + acc1[j]) * invl);
  }
}

// ---------------------------------------------------------------------------
// Output projection (MFMA): out[4096][1024] = ctxB @ Wz  (B from WzT)
// ---------------------------------------------------------------------------
__global__ __launch_bounds__(256, 4) void outproj_mfma_kernel(
    const bf16* __restrict__ A,   // [4096][1024] bf16
    const bf16* __restrict__ Bt,  // [1024 n][1024 k] bf16
    float* __restrict__ C) {
  const int tid = threadIdx.x;
  const int w = tid >> 6, lane = tid & 63, l15 = lane & 15, hi = lane >> 4;
  const int m0 = blockIdx.y * 64 + w * 16;
  const int n0 = blockIdx.x * 64;
  f32x4 acc[4] = {{0.f, 0.f, 0.f, 0.f}, {0.f, 0.f, 0.f, 0.f},
                  {0.f, 0.f, 0.f, 0.f}, {0.f, 0.f, 0.f, 0.f}};
  for (int kc = 0; kc < 1024; kc += 32) {
    const short8 a = *(const short8*)(A + (size_t)(m0 + l15) * 1024 + kc + hi * 8);
#pragma unroll
    for (int nt = 0; nt < 4; ++nt) {
      const short8 b = *(const short8*)(
          Bt + (size_t)(n0 + nt * 16 + l15) * 1024 + kc + hi * 8);
      acc[nt] = mfma16(a, b, acc[nt]);
    }
  }
#pragma unroll
  for (int nt = 0; nt < 4; ++nt)
#pragma unroll
    for (int j = 0; j < 4; ++j)
      C[(size_t)(m0 + hi * 4 + j) * 1024 + n0 + nt * 16 + l15] = acc[nt][j];
}

// ---------------------------------------------------------------------------
extern "C" void kernel_launch(void* const* d_in, const int* in_sizes, int n_in,
                              void* d_out, int out_size, void* d_ws,
                              size_t ws_size, hipStream_t stream) {
  const float* x = (const float*)d_in[0];
  const float* WQ = (const float*)d_in[1];
  const float* WK = (const float*)d_in[2];
  const float* WV = (const float*)d_in[3];
  const float* WZ = (const float*)d_in[4];
  const float* posK = (const float*)d_in[5];
  const float* posV = (const float*)d_in[6];
  const float* maskp = (const float*)d_in[7];
  const int* pos = (const int*)d_in[8];
  float* out = (float*)d_out;

  char* p = (char*)d_ws;
  bf16* Qb = (bf16*)p;        p += (size_t)64 * 1024 * 64 * 2;   // 8 MB
  bf16* Kb = (bf16*)p;        p += (size_t)64 * 1024 * 64 * 2;   // 8 MB
  bf16* Vb = (bf16*)p;        p += (size_t)64 * 1024 * 64 * 2;   // 8 MB
  bf16* Vt = (bf16*)p;        p += (size_t)64 * 64 * 1024 * 2;   // 8 MB
  bf16* posKbf = (bf16*)p;    p += (size_t)2048 * 64 * 2;        // 256 KB
  bf16* WzT = (bf16*)p;       p += (size_t)1024 * 1024 * 2;      // 2 MB
  bf16* Pws = (bf16*)p;       p += (size_t)256 * 64 * 1024 * 2;  // 32 MB
  float* l_ws = (float*)p;    p += (size_t)64 * 1024 * 4;        // 256 KB
  float* ctxU = (float*)p;    p += (size_t)4 * 1024 * 1024 * 4;  // 16 MB
  bf16* ctxB = (bf16*)p;      p += (size_t)4 * 1024 * 1024 * 2;  // 8 MB

  prep_posk_kernel<<<512, 256, 0, stream>>>(posK, posKbf);
  trans_wz_kernel<<<dim3(16, 16), 256, 0, stream>>>(WZ, WzT);
  qkv_kernel<<<dim3(16, 64), 256, 0, stream>>>(x, WQ, WK, WV, Qb, Kb, Vb);
  trans_v_kernel<<<dim3(16, 64), 256, 0, stream>>>(Vb, Vt);

  for (int slab = 0; slab < 4; ++slab) {
    score_pv_kernel<<<dim3(16, 64), 256, 0, stream>>>(
        Qb, Kb, posKbf, Vt, maskp, pos, Pws, l_ws, ctxU, slab);
    pv_gather_kernel<<<256, 512, 0, stream>>>(Pws, posV, pos, l_ws, ctxU,
                                              ctxB, slab);
  }
  outproj_mfma_kernel<<<dim3(16, 64), 256, 0, stream>>>(ctxB, WzT, out);
}

// Round 4
// 522.489 us; speedup vs baseline: 8.7788x; 1.2267x over previous
//
#include <hip/hip_runtime.h>
#include <hip/hip_bf16.h>

#define BB 4
#define TT 1024
#define DM 1024
#define HH 16

typedef __attribute__((ext_vector_type(8))) short short8;
typedef __attribute__((ext_vector_type(4))) short short4v;
typedef __attribute__((ext_vector_type(4))) float f32x4;
typedef __hip_bfloat16 bf16;

__device__ __forceinline__ f32x4 mfma16(short8 a, short8 b, f32x4 c) {
  return __builtin_amdgcn_mfma_f32_16x16x32_bf16(a, b, c, 0, 0, 0);
}

// ---------------------------------------------------------------------------
// x fp32 -> bf16, 8 elems/thread. grid 2048.
// ---------------------------------------------------------------------------
__global__ __launch_bounds__(256) void xb_kernel(
    const float* __restrict__ x, bf16* __restrict__ xb) {
  const size_t i = ((size_t)blockIdx.x * 256 + threadIdx.x) * 8;
  bf16 tmp[8];
#pragma unroll
  for (int j = 0; j < 8; ++j) tmp[j] = __float2bfloat16(x[i + j]);
  *(short8*)(xb + i) = *(const short8*)tmp;
}

// ---------------------------------------------------------------------------
// W_{Q,K,V} fp32 [16][64 d][64 e] -> Wt bf16 [3][16][64 e][64 d] (transposed)
// grid (16 h, 3 m)
// ---------------------------------------------------------------------------
__global__ __launch_bounds__(256) void prep_w_kernel(
    const float* __restrict__ WQ, const float* __restrict__ WK,
    const float* __restrict__ WV, bf16* __restrict__ Wt) {
  __shared__ bf16 tl[64][72];
  const int h = blockIdx.x, m = blockIdx.y;
  const float* W = (m == 0 ? WQ : (m == 1 ? WK : WV)) + h * 4096;
  const int tid = threadIdx.x;
  const int r = tid >> 2, c = (tid & 3) * 16;
#pragma unroll
  for (int i = 0; i < 16; ++i)
    tl[r][c + i] = __float2bfloat16(W[r * 64 + c + i]);  // tl[d][e]
  __syncthreads();
  bf16* o = Wt + ((size_t)(m * 16 + h) * 64 + r) * 64 + c;  // [e=r][d=c..]
#pragma unroll
  for (int i = 0; i < 16; ++i) o[i] = tl[c + i][r];
}

// ---------------------------------------------------------------------------
// prep: posK fp32 [2047][64] -> bf16 [2048][64] (row 2047 zeroed)
// ---------------------------------------------------------------------------
__global__ __launch_bounds__(256) void prep_posk_kernel(
    const float* __restrict__ posK, bf16* __restrict__ posKbf) {
  const int idx = blockIdx.x * 256 + threadIdx.x;
  const int p = idx >> 6, d = idx & 63;
  const float v = (p < 2047) ? posK[(size_t)p * 64 + d] : 0.f;
  posKbf[idx] = __float2bfloat16(v);
}

// ---------------------------------------------------------------------------
// prep: WzT bf16 [n][k] = Wz fp32 [k][n]
// ---------------------------------------------------------------------------
__global__ __launch_bounds__(256) void trans_wz_kernel(
    const float* __restrict__ Wz, bf16* __restrict__ WzT) {
  __shared__ bf16 tile[64][72];
  const int k0 = blockIdx.y * 64, n0 = blockIdx.x * 64;
  const int tid = threadIdx.x;
  const int r = tid >> 2, c = (tid & 3) * 16;
  const float* s = Wz + (size_t)(k0 + r) * 1024 + n0 + c;
#pragma unroll
  for (int i = 0; i < 16; ++i) tile[r][c + i] = __float2bfloat16(s[i]);
  __syncthreads();
  const int n = tid >> 2;
  bf16* o = WzT + (size_t)(n0 + n) * 1024 + k0 + c;
#pragma unroll
  for (int i = 0; i < 16; ++i) o[i] = tile[c + i][n];
}

// ---------------------------------------------------------------------------
// transpose V: [bh][1024][64] bf16 -> Vt [bh][64][1024] bf16
// ---------------------------------------------------------------------------
__global__ __launch_bounds__(256) void trans_v_kernel(
    const bf16* __restrict__ src, bf16* __restrict__ dst) {
  __shared__ bf16 tile[64][72];
  const int bh = blockIdx.y, t0 = blockIdx.x * 64;
  const int tid = threadIdx.x;
  const int r = tid >> 2, c = (tid & 3) * 16;
  const bf16* s = src + ((size_t)bh * TT + t0 + r) * 64 + c;
  *(short8*)(&tile[r][c]) = *(const short8*)(s);
  *(short8*)(&tile[r][c + 8]) = *(const short8*)(s + 8);
  __syncthreads();
  const int d = tid >> 2;
  bf16* o = dst + ((size_t)bh * 64 + d) * TT + t0 + c;
#pragma unroll
  for (int i = 0; i < 16; ++i) o[i] = tile[c + i][d];
}

// ---------------------------------------------------------------------------
// QKV projection via MFMA. grid (16 ttiles, 64 bh), block 256 (4 waves).
// Q[t,e] = sum_d xb[b,t,h*64+d] * WQ[h,d,e]; A = x rows, B = Wt rows (e).
// ---------------------------------------------------------------------------
__global__ __launch_bounds__(256) void qkv_mfma_kernel(
    const bf16* __restrict__ xb, const bf16* __restrict__ Wt,
    bf16* __restrict__ Qg, bf16* __restrict__ Kg, bf16* __restrict__ Vg) {
  __shared__ __align__(16) bf16 xs[64 * 72];
  const int bh = blockIdx.y;
  const int b = bh >> 4, h = bh & 15;
  const int t0 = blockIdx.x * 64;
  const int tid = threadIdx.x;
  const int w = tid >> 6, lane = tid & 63, l15 = lane & 15, hi = lane >> 4;

  {
    const int r = tid >> 2, c = (tid & 3) * 16;
    const bf16* src = xb + ((size_t)b * TT + t0 + r) * DM + h * 64 + c;
    *(short8*)(xs + r * 72 + c) = *(const short8*)(src);
    *(short8*)(xs + r * 72 + c + 8) = *(const short8*)(src + 8);
  }
  __syncthreads();

  f32x4 aQ[4] = {{0.f, 0.f, 0.f, 0.f}, {0.f, 0.f, 0.f, 0.f},
                 {0.f, 0.f, 0.f, 0.f}, {0.f, 0.f, 0.f, 0.f}};
  f32x4 aK[4] = {{0.f, 0.f, 0.f, 0.f}, {0.f, 0.f, 0.f, 0.f},
                 {0.f, 0.f, 0.f, 0.f}, {0.f, 0.f, 0.f, 0.f}};
  f32x4 aV[4] = {{0.f, 0.f, 0.f, 0.f}, {0.f, 0.f, 0.f, 0.f},
                 {0.f, 0.f, 0.f, 0.f}, {0.f, 0.f, 0.f, 0.f}};
  const bf16* WtQ = Wt + (size_t)h * 4096;
  const bf16* WtK = Wt + (size_t)(16 + h) * 4096;
  const bf16* WtV = Wt + (size_t)(32 + h) * 4096;
#pragma unroll
  for (int kc = 0; kc < 2; ++kc) {
    const short8 a =
        *(const short8*)(xs + (w * 16 + l15) * 72 + kc * 32 + hi * 8);
#pragma unroll
    for (int nt = 0; nt < 4; ++nt) {
      const size_t wo = (size_t)(nt * 16 + l15) * 64 + kc * 32 + hi * 8;
      aQ[nt] = mfma16(a, *(const short8*)(WtQ + wo), aQ[nt]);
      aK[nt] = mfma16(a, *(const short8*)(WtK + wo), aK[nt]);
      aV[nt] = mfma16(a, *(const short8*)(WtV + wo), aV[nt]);
    }
  }
  const int t = t0 + w * 16 + hi * 4;
#pragma unroll
  for (int nt = 0; nt < 4; ++nt) {
#pragma unroll
    for (int j = 0; j < 4; ++j) {
      const size_t o = ((size_t)bh * TT + t + j) * 64 + nt * 16 + l15;
      Qg[o] = __float2bfloat16(aQ[nt][j]);
      Kg[o] = __float2bfloat16(aK[nt][j]);
      Vg[o] = __float2bfloat16(aV[nt][j]);
    }
  }
}

// ---------------------------------------------------------------------------
// Fused score kernel (unchanged from round 3).
// ---------------------------------------------------------------------------
#define QP_S 2052
#define KSH_S 72
#define PSM_S 72
#define POS_S 66

__global__ __launch_bounds__(256, 2) void score_pv_kernel(
    const bf16* __restrict__ Qb,
    const bf16* __restrict__ Kb,
    const bf16* __restrict__ posKbf,
    const bf16* __restrict__ Vt,
    const float* __restrict__ maskp,
    const int* __restrict__ pos,
    bf16* __restrict__ Pws,        // [256 qlocal][64 bh][1024 k]
    float* __restrict__ l_ws,      // [64 bh][1024 q]
    float* __restrict__ ctxU,      // [b][t][1024] fp32 unnormalized
    int slab) {
  __shared__ __align__(16) bf16 QPsh[16 * QP_S];
  __shared__ __align__(16) bf16 Ksh[64 * KSH_S];
  __shared__ __align__(16) bf16 Psm[16 * PSM_S];
  __shared__ unsigned short possh[16 * POS_S];
  __shared__ float lred[4][16];

  const int bh = blockIdx.y;
  const int qt = blockIdx.x;
  const int qlocal0 = qt * 16;
  const int qg0 = slab * 256 + qlocal0;
  const int tid = threadIdx.x;
  const int w = tid >> 6;
  const int lane = tid & 63;
  const int l15 = lane & 15;
  const int hi = lane >> 4;

  const bf16* Qrow = Qb + ((size_t)bh * TT + qg0 + l15) * 64 + hi * 8;
  const short8 aq0 = *(const short8*)(Qrow);
  const short8 aq1 = *(const short8*)(Qrow + 32);

  // ---- QP phase: wave w covers p-tiles w*32 .. w*32+31
  for (int i = 0; i < 32; ++i) {
    const int pt = w * 32 + i;
    const bf16* Kp = posKbf + ((size_t)(pt * 16 + l15)) * 64 + hi * 8;
    const short8 b0 = *(const short8*)(Kp);
    const short8 b1 = *(const short8*)(Kp + 32);
    f32x4 acc = {0.f, 0.f, 0.f, 0.f};
    acc = mfma16(aq0, b0, acc);
    acc = mfma16(aq1, b1, acc);
#pragma unroll
    for (int j = 0; j < 4; ++j)
      QPsh[(hi * 4 + j) * QP_S + pt * 16 + l15] = __float2bfloat16(acc[j]);
  }
  __syncthreads();

  f32x4 acc_pv = {0.f, 0.f, 0.f, 0.f};
  float lp[4] = {0.f, 0.f, 0.f, 0.f};
  const bf16* Kbh = Kb + (size_t)bh * TT * 64;
  const bf16* Vtbh = Vt + (size_t)bh * 64 * TT;

  for (int it = 0; it < 16; ++it) {
    const int k0 = it * 64;
    {
      const int r = tid >> 2, c = (tid & 3) * 16;
      const bf16* src = Kbh + (size_t)(k0 + r) * 64 + c;
      *(short8*)(Ksh + r * KSH_S + c) = *(const short8*)(src);
      *(short8*)(Ksh + r * KSH_S + c + 8) = *(const short8*)(src + 8);
      const int pr = tid >> 4, pc = (tid & 15) * 4;
      const int* ps = pos + (size_t)(qg0 + pr) * TT + k0 + pc;
      possh[pr * POS_S + pc + 0] = (unsigned short)ps[0];
      possh[pr * POS_S + pc + 1] = (unsigned short)ps[1];
      possh[pr * POS_S + pc + 2] = (unsigned short)ps[2];
      possh[pr * POS_S + pc + 3] = (unsigned short)ps[3];
    }
    __syncthreads();
    const bf16* krow = Ksh + (w * 16 + l15) * KSH_S + hi * 8;
    const short8 b0 = *(const short8*)(krow);
    const short8 b1 = *(const short8*)(krow + 32);
    f32x4 s = {0.f, 0.f, 0.f, 0.f};
    s = mfma16(aq0, b0, s);
    s = mfma16(aq1, b1, s);
    const int kk = w * 16 + l15;
#pragma unroll
    for (int j = 0; j < 4; ++j) {
      const int q = hi * 4 + j;
      const int p = possh[q * POS_S + kk];
      float sv = s[j] + __bfloat162float(QPsh[q * QP_S + p]);
      sv = (sv + maskp[(size_t)(qg0 + q) * TT + k0 + kk]) * 0.125f;
      const float pe = __expf(sv);
      lp[j] += pe;
      Psm[q * PSM_S + kk] = __float2bfloat16(pe);
    }
    __syncthreads();
    {
      const int r = tid >> 4, c = (tid & 15) * 4;
      *(short4v*)(Pws + ((size_t)(qlocal0 + r) * 64 + bh) * TT + k0 + c) =
          *(const short4v*)(Psm + r * PSM_S + c);
    }
#pragma unroll
    for (int kc = 0; kc < 2; ++kc) {
      const short8 pa = *(const short8*)(Psm + l15 * PSM_S + kc * 32 + hi * 8);
      const short8 bv = *(const short8*)(
          Vtbh + (size_t)(w * 16 + l15) * TT + k0 + kc * 32 + hi * 8);
      acc_pv = mfma16(pa, bv, acc_pv);
    }
    __syncthreads();
  }

#pragma unroll
  for (int j = 0; j < 4; ++j) {
    float v = lp[j];
    v += __shfl_xor(v, 1);
    v += __shfl_xor(v, 2);
    v += __shfl_xor(v, 4);
    v += __shfl_xor(v, 8);
    if (l15 == 0) lred[w][hi * 4 + j] = v;
  }
  __syncthreads();
  if (tid < 16) {
    const float l = lred[0][tid] + lred[1][tid] + lred[2][tid] + lred[3][tid];
    l_ws[(size_t)bh * TT + qg0 + tid] = l;
  }
  {
    const int b = bh >> 4, h = bh & 15;
#pragma unroll
    for (int j = 0; j < 4; ++j) {
      const int q = hi * 4 + j;
      ctxU[((size_t)b * TT + qg0 + q) * DM + h * 64 + w * 16 + l15] = acc_pv[j];
    }
  }
}

// ---------------------------------------------------------------------------
// PV gather via MFMA: one block per q. ctxPV = P[64bh x 1024k] @ PVt^T.
// Fuses ctxU add + 1/l normalize + bf16 ctxB write. grid 256/slab, block 256.
// ---------------------------------------------------------------------------
#define PVT_S 72
#define PSH_S 72
__global__ __launch_bounds__(256) void pv_mfma_kernel(
    const bf16* __restrict__ Pws,
    const float* __restrict__ posV,
    const int* __restrict__ pos,
    const float* __restrict__ l_ws,
    const float* __restrict__ ctxU,
    bf16* __restrict__ ctxB,
    int slab) {
  __shared__ __align__(16) bf16 PVt[64 * PVT_S];  // [d][k] transposed
  __shared__ __align__(16) bf16 Psh[64 * PSH_S];  // [bh][k]
  __shared__ unsigned short possh[1024];

  const int qlocal = blockIdx.x;
  const int q = slab * 256 + qlocal;
  const int tid = threadIdx.x;
  const int w = tid >> 6, lane = tid & 63, l15 = lane & 15, hi = lane >> 4;

  for (int i = tid; i < 1024; i += 256)
    possh[i] = (unsigned short)pos[(size_t)q * TT + i];
  __syncthreads();

  f32x4 acc[4] = {{0.f, 0.f, 0.f, 0.f}, {0.f, 0.f, 0.f, 0.f},
                  {0.f, 0.f, 0.f, 0.f}, {0.f, 0.f, 0.f, 0.f}};

  for (int it = 0; it < 16; ++it) {
    const int k0 = it * 64;
    // stage P tile [64 bh][64 k] (coalesced)
    {
      const int r = tid >> 2, c = (tid & 3) * 16;
      const bf16* psrc = Pws + ((size_t)qlocal * 64 + r) * TT + k0 + c;
      *(short8*)(Psh + r * PSH_S + c) = *(const short8*)(psrc);
      *(short8*)(Psh + r * PSH_S + c + 8) = *(const short8*)(psrc + 8);
    }
    // stage gathered posV rows transposed: lane = k-row, wave picks d-chunk.
    // Column writes: consecutive lanes -> consecutive k -> 2-way-free banks.
    {
      const int kr = lane;
      const int dc = w * 16;
      const int p = possh[k0 + kr];
      const float* src = posV + (size_t)p * 64 + dc;
#pragma unroll
      for (int ii = 0; ii < 16; ii += 4) {
        const f32x4 v = *(const f32x4*)(src + ii);
        PVt[(dc + ii + 0) * PVT_S + kr] = __float2bfloat16(v[0]);
        PVt[(dc + ii + 1) * PVT_S + kr] = __float2bfloat16(v[1]);
        PVt[(dc + ii + 2) * PVT_S + kr] = __float2bfloat16(v[2]);
        PVt[(dc + ii + 3) * PVT_S + kr] = __float2bfloat16(v[3]);
      }
    }
    __syncthreads();
#pragma unroll
    for (int kc = 0; kc < 2; ++kc) {
      const short8 a =
          *(const short8*)(Psh + (w * 16 + l15) * PSH_S + kc * 32 + hi * 8);
#pragma unroll
      for (int nt = 0; nt < 4; ++nt) {
        const short8 bv = *(const short8*)(PVt + (nt * 16 + l15) * PVT_S +
                                           kc * 32 + hi * 8);
        acc[nt] = mfma16(a, bv, acc[nt]);
      }
    }
    __syncthreads();
  }

  const int bh0 = w * 16 + hi * 4;
#pragma unroll
  for (int j = 0; j < 4; ++j) {
    const int bh = bh0 + j;
    const int b = bh >> 4, h = bh & 15;
    const float invl = 1.0f / l_ws[(size_t)bh * TT + q];
    const size_t base = ((size_t)b * TT + q) * DM + h * 64;
#pragma unroll
    for (int nt = 0; nt < 4; ++nt) {
      const size_t o = base + nt * 16 + l15;
      ctxB[o] = __float2bfloat16((ctxU[o] + acc[nt][j]) * invl);
    }
  }
}

// ---------------------------------------------------------------------------
// Output projection (MFMA): out[4096][1024] = ctxB @ Wz  (B from WzT)
// ---------------------------------------------------------------------------
__global__ __launch_bounds__(256, 4) void outproj_mfma_kernel(
    const bf16* __restrict__ A,
    const bf16* __restrict__ Bt,
    float* __restrict__ C) {
  const int tid = threadIdx.x;
  const int w = tid >> 6, lane = tid & 63, l15 = lane & 15, hi = lane >> 4;
  const int m0 = blockIdx.y * 64 + w * 16;
  const int n0 = blockIdx.x * 64;
  f32x4 acc[4] = {{0.f, 0.f, 0.f, 0.f}, {0.f, 0.f, 0.f, 0.f},
                  {0.f, 0.f, 0.f, 0.f}, {0.f, 0.f, 0.f, 0.f}};
  for (int kc = 0; kc < 1024; kc += 32) {
    const short8 a =
        *(const short8*)(A + (size_t)(m0 + l15) * 1024 + kc + hi * 8);
#pragma unroll
    for (int nt = 0; nt < 4; ++nt) {
      const short8 b = *(const short8*)(
          Bt + (size_t)(n0 + nt * 16 + l15) * 1024 + kc + hi * 8);
      acc[nt] = mfma16(a, b, acc[nt]);
    }
  }
#pragma unroll
  for (int nt = 0; nt < 4; ++nt)
#pragma unroll
    for (int j = 0; j < 4; ++j)
      C[(size_t)(m0 + hi * 4 + j) * 1024 + n0 + nt * 16 + l15] = acc[nt][j];
}

// ---------------------------------------------------------------------------
extern "C" void kernel_launch(void* const* d_in, const int* in_sizes, int n_in,
                              void* d_out, int out_size, void* d_ws,
                              size_t ws_size, hipStream_t stream) {
  const float* x = (const float*)d_in[0];
  const float* WQ = (const float*)d_in[1];
  const float* WK = (const float*)d_in[2];
  const float* WV = (const float*)d_in[3];
  const float* WZ = (const float*)d_in[4];
  const float* posK = (const float*)d_in[5];
  const float* posV = (const float*)d_in[6];
  const float* maskp = (const float*)d_in[7];
  const int* pos = (const int*)d_in[8];
  float* out = (float*)d_out;

  char* p = (char*)d_ws;
  bf16* Qb = (bf16*)p;        p += (size_t)64 * 1024 * 64 * 2;   // 8 MB
  bf16* Kb = (bf16*)p;        p += (size_t)64 * 1024 * 64 * 2;   // 8 MB
  bf16* Vb = (bf16*)p;        p += (size_t)64 * 1024 * 64 * 2;   // 8 MB
  bf16* Vt = (bf16*)p;        p += (size_t)64 * 64 * 1024 * 2;   // 8 MB
  bf16* posKbf = (bf16*)p;    p += (size_t)2048 * 64 * 2;        // 256 KB
  bf16* WzT = (bf16*)p;       p += (size_t)1024 * 1024 * 2;      // 2 MB
  bf16* Pws = (bf16*)p;       p += (size_t)256 * 64 * 1024 * 2;  // 32 MB
  float* l_ws = (float*)p;    p += (size_t)64 * 1024 * 4;        // 256 KB
  float* ctxU = (float*)p;    p += (size_t)4 * 1024 * 1024 * 4;  // 16 MB
  bf16* ctxB = (bf16*)p;      p += (size_t)4 * 1024 * 1024 * 2;  // 8 MB

  // Aliases (dead-range reuse, safe under stream ordering):
  bf16* xb = (bf16*)ctxU;  // xb dead after qkv; ctxU written later
  bf16* Wt = ctxB;         // Wt dead after qkv; ctxB written later

  xb_kernel<<<2048, 256, 0, stream>>>(x, xb);
  prep_w_kernel<<<dim3(16, 3), 256, 0, stream>>>(WQ, WK, WV, Wt);
  prep_posk_kernel<<<512, 256, 0, stream>>>(posK, posKbf);
  trans_wz_kernel<<<dim3(16, 16), 256, 0, stream>>>(WZ, WzT);
  qkv_mfma_kernel<<<dim3(16, 64), 256, 0, stream>>>(xb, Wt, Qb, Kb, Vb);
  trans_v_kernel<<<dim3(16, 64), 256, 0, stream>>>(Vb, Vt);

  for (int slab = 0; slab < 4; ++slab) {
    score_pv_kernel<<<dim3(16, 64), 256, 0, stream>>>(
        Qb, Kb, posKbf, Vt, maskp, pos, Pws, l_ws, ctxU, slab);
    pv_mfma_kernel<<<256, 256, 0, stream>>>(Pws, posV, pos, l_ws, ctxU, ctxB,
                                            slab);
  }
  outproj_mfma_kernel<<<dim3(16, 64), 256, 0, stream>>>(ctxB, WzT, out);
}

// Round 5
// 497.547 us; speedup vs baseline: 9.2189x; 1.0501x over previous
//
#include <hip/hip_runtime.h>
#include <hip/hip_bf16.h>

#define BB 4
#define TT 1024
#define DM 1024
#define HH 16

typedef __attribute__((ext_vector_type(8))) short short8;
typedef __attribute__((ext_vector_type(4))) short short4v;
typedef __attribute__((ext_vector_type(4))) float f32x4;
typedef __hip_bfloat16 bf16;

__device__ __forceinline__ f32x4 mfma16(short8 a, short8 b, f32x4 c) {
  return __builtin_amdgcn_mfma_f32_16x16x32_bf16(a, b, c, 0, 0, 0);
}

// ---------------------------------------------------------------------------
// x fp32 -> bf16, 8 elems/thread. grid 2048.
// ---------------------------------------------------------------------------
__global__ __launch_bounds__(256) void xb_kernel(
    const float* __restrict__ x, bf16* __restrict__ xb) {
  const size_t i = ((size_t)blockIdx.x * 256 + threadIdx.x) * 8;
  bf16 tmp[8];
#pragma unroll
  for (int j = 0; j < 8; ++j) tmp[j] = __float2bfloat16(x[i + j]);
  *(short8*)(xb + i) = *(const short8*)tmp;
}

// ---------------------------------------------------------------------------
// W_{Q,K,V} fp32 [16][64 d][64 e] -> Wt bf16 [3][16][64 e][64 d] (transposed)
// grid (16 h, 3 m)
// ---------------------------------------------------------------------------
__global__ __launch_bounds__(256) void prep_w_kernel(
    const float* __restrict__ WQ, const float* __restrict__ WK,
    const float* __restrict__ WV, bf16* __restrict__ Wt) {
  __shared__ bf16 tl[64][72];
  const int h = blockIdx.x, m = blockIdx.y;
  const float* W = (m == 0 ? WQ : (m == 1 ? WK : WV)) + h * 4096;
  const int tid = threadIdx.x;
  const int r = tid >> 2, c = (tid & 3) * 16;
#pragma unroll
  for (int i = 0; i < 16; ++i)
    tl[r][c + i] = __float2bfloat16(W[r * 64 + c + i]);  // tl[d][e]
  __syncthreads();
  bf16* o = Wt + ((size_t)(m * 16 + h) * 64 + r) * 64 + c;  // [e=r][d=c..]
#pragma unroll
  for (int i = 0; i < 16; ++i) o[i] = tl[c + i][r];
}

// ---------------------------------------------------------------------------
// prep: posK fp32 [2047][64] -> bf16 [2048][64] (row 2047 zeroed)
// ---------------------------------------------------------------------------
__global__ __launch_bounds__(256) void prep_posk_kernel(
    const float* __restrict__ posK, bf16* __restrict__ posKbf) {
  const int idx = blockIdx.x * 256 + threadIdx.x;
  const int p = idx >> 6, d = idx & 63;
  const float v = (p < 2047) ? posK[(size_t)p * 64 + d] : 0.f;
  posKbf[idx] = __float2bfloat16(v);
}

// ---------------------------------------------------------------------------
// prep: WzT bf16 [n][k] = Wz fp32 [k][n]
// ---------------------------------------------------------------------------
__global__ __launch_bounds__(256) void trans_wz_kernel(
    const float* __restrict__ Wz, bf16* __restrict__ WzT) {
  __shared__ bf16 tile[64][72];
  const int k0 = blockIdx.y * 64, n0 = blockIdx.x * 64;
  const int tid = threadIdx.x;
  const int r = tid >> 2, c = (tid & 3) * 16;
  const float* s = Wz + (size_t)(k0 + r) * 1024 + n0 + c;
#pragma unroll
  for (int i = 0; i < 16; ++i) tile[r][c + i] = __float2bfloat16(s[i]);
  __syncthreads();
  const int n = tid >> 2;
  bf16* o = WzT + (size_t)(n0 + n) * 1024 + k0 + c;
#pragma unroll
  for (int i = 0; i < 16; ++i) o[i] = tile[c + i][n];
}

// ---------------------------------------------------------------------------
// transpose V: [bh][1024][64] bf16 -> Vt [bh][64][1024] bf16
// ---------------------------------------------------------------------------
__global__ __launch_bounds__(256) void trans_v_kernel(
    const bf16* __restrict__ src, bf16* __restrict__ dst) {
  __shared__ bf16 tile[64][72];
  const int bh = blockIdx.y, t0 = blockIdx.x * 64;
  const int tid = threadIdx.x;
  const int r = tid >> 2, c = (tid & 3) * 16;
  const bf16* s = src + ((size_t)bh * TT + t0 + r) * 64 + c;
  *(short8*)(&tile[r][c]) = *(const short8*)(s);
  *(short8*)(&tile[r][c + 8]) = *(const short8*)(s + 8);
  __syncthreads();
  const int d = tid >> 2;
  bf16* o = dst + ((size_t)bh * 64 + d) * TT + t0 + c;
#pragma unroll
  for (int i = 0; i < 16; ++i) o[i] = tile[c + i][d];
}

// ---------------------------------------------------------------------------
// QKV projection via MFMA. grid (16 ttiles, 64 bh), block 256 (4 waves).
// ---------------------------------------------------------------------------
__global__ __launch_bounds__(256) void qkv_mfma_kernel(
    const bf16* __restrict__ xb, const bf16* __restrict__ Wt,
    bf16* __restrict__ Qg, bf16* __restrict__ Kg, bf16* __restrict__ Vg) {
  __shared__ __align__(16) bf16 xs[64 * 72];
  const int bh = blockIdx.y;
  const int b = bh >> 4, h = bh & 15;
  const int t0 = blockIdx.x * 64;
  const int tid = threadIdx.x;
  const int w = tid >> 6, lane = tid & 63, l15 = lane & 15, hi = lane >> 4;

  {
    const int r = tid >> 2, c = (tid & 3) * 16;
    const bf16* src = xb + ((size_t)b * TT + t0 + r) * DM + h * 64 + c;
    *(short8*)(xs + r * 72 + c) = *(const short8*)(src);
    *(short8*)(xs + r * 72 + c + 8) = *(const short8*)(src + 8);
  }
  __syncthreads();

  f32x4 aQ[4] = {{0.f, 0.f, 0.f, 0.f}, {0.f, 0.f, 0.f, 0.f},
                 {0.f, 0.f, 0.f, 0.f}, {0.f, 0.f, 0.f, 0.f}};
  f32x4 aK[4] = {{0.f, 0.f, 0.f, 0.f}, {0.f, 0.f, 0.f, 0.f},
                 {0.f, 0.f, 0.f, 0.f}, {0.f, 0.f, 0.f, 0.f}};
  f32x4 aV[4] = {{0.f, 0.f, 0.f, 0.f}, {0.f, 0.f, 0.f, 0.f},
                 {0.f, 0.f, 0.f, 0.f}, {0.f, 0.f, 0.f, 0.f}};
  const bf16* WtQ = Wt + (size_t)h * 4096;
  const bf16* WtK = Wt + (size_t)(16 + h) * 4096;
  const bf16* WtV = Wt + (size_t)(32 + h) * 4096;
#pragma unroll
  for (int kc = 0; kc < 2; ++kc) {
    const short8 a =
        *(const short8*)(xs + (w * 16 + l15) * 72 + kc * 32 + hi * 8);
#pragma unroll
    for (int nt = 0; nt < 4; ++nt) {
      const size_t wo = (size_t)(nt * 16 + l15) * 64 + kc * 32 + hi * 8;
      aQ[nt] = mfma16(a, *(const short8*)(WtQ + wo), aQ[nt]);
      aK[nt] = mfma16(a, *(const short8*)(WtK + wo), aK[nt]);
      aV[nt] = mfma16(a, *(const short8*)(WtV + wo), aV[nt]);
    }
  }
  const int t = t0 + w * 16 + hi * 4;
#pragma unroll
  for (int nt = 0; nt < 4; ++nt) {
#pragma unroll
    for (int j = 0; j < 4; ++j) {
      const size_t o = ((size_t)bh * TT + t + j) * 64 + nt * 16 + l15;
      Qg[o] = __float2bfloat16(aQ[nt][j]);
      Kg[o] = __float2bfloat16(aK[nt][j]);
      Vg[o] = __float2bfloat16(aV[nt][j]);
    }
  }
}

// ---------------------------------------------------------------------------
// Fused score kernel, v2:
//  - QP table stored fp8-e4m3 in LDS (32 KB) -> 4 blocks/CU (16 waves)
//  - K and Vt b-frags read directly from global (L2-hot), no Ksh
//  - pos/mask read directly from global, no possh
//  - Psm double-buffered -> exactly 1 barrier per k-tile
// grid (16 qtiles, 64 bh), block 256 (4 waves).
// ---------------------------------------------------------------------------
#define QP8_S 2052   // bytes per q row of fp8 QP (2047 used + pad)
#define PSM_S 72

__global__ __launch_bounds__(256, 4) void score_pv_kernel(
    const bf16* __restrict__ Qb,
    const bf16* __restrict__ Kb,
    const bf16* __restrict__ posKbf,
    const bf16* __restrict__ Vt,
    const float* __restrict__ maskp,
    const int* __restrict__ pos,
    bf16* __restrict__ Pws,        // [256 qlocal][64 bh][1024 k]
    float* __restrict__ l_ws,      // [64 bh][1024 q]
    float* __restrict__ ctxU,      // [b][t][1024] fp32 unnormalized
    int slab) {
  __shared__ __align__(16) unsigned char QPsh[16 * QP8_S];  // 32832 B
  __shared__ __align__(16) bf16 Psm[2][16 * PSM_S];         // 4608 B
  __shared__ float lred[4][16];                             // 256 B

  const int bh = blockIdx.y;
  const int qt = blockIdx.x;
  const int qlocal0 = qt * 16;
  const int qg0 = slab * 256 + qlocal0;
  const int tid = threadIdx.x;
  const int w = tid >> 6;
  const int lane = tid & 63;
  const int l15 = lane & 15;
  const int hi = lane >> 4;

  const bf16* Qrow = Qb + ((size_t)bh * TT + qg0 + l15) * 64 + hi * 8;
  const short8 aq0 = *(const short8*)(Qrow);
  const short8 aq1 = *(const short8*)(Qrow + 32);

  // ---- QP phase: wave w covers p-tiles w*32 .. w*32+31; store fp8
  for (int i = 0; i < 32; ++i) {
    const int pt = w * 32 + i;
    const bf16* Kp = posKbf + ((size_t)(pt * 16 + l15)) * 64 + hi * 8;
    const short8 b0 = *(const short8*)(Kp);
    const short8 b1 = *(const short8*)(Kp + 32);
    f32x4 acc = {0.f, 0.f, 0.f, 0.f};
    acc = mfma16(aq0, b0, acc);
    acc = mfma16(aq1, b1, acc);
    const int p01 = __builtin_amdgcn_cvt_pk_fp8_f32(acc[0], acc[1], 0, false);
    const int p23 = __builtin_amdgcn_cvt_pk_fp8_f32(acc[2], acc[3], 0, false);
    const int off = pt * 16 + l15;
    QPsh[(hi * 4 + 0) * QP8_S + off] = (unsigned char)(p01 & 0xff);
    QPsh[(hi * 4 + 1) * QP8_S + off] = (unsigned char)((p01 >> 8) & 0xff);
    QPsh[(hi * 4 + 2) * QP8_S + off] = (unsigned char)(p23 & 0xff);
    QPsh[(hi * 4 + 3) * QP8_S + off] = (unsigned char)((p23 >> 8) & 0xff);
  }
  __syncthreads();

  // wave w owns PV output d-tile [w*16, w*16+16)
  f32x4 acc_pv = {0.f, 0.f, 0.f, 0.f};
  float lp[4] = {0.f, 0.f, 0.f, 0.f};
  const int kk = w * 16 + l15;
  const bf16* Kbh = Kb + (size_t)bh * TT * 64;
  const bf16* Vtrow = Vt + ((size_t)bh * 64 + w * 16 + l15) * TT;

  for (int it = 0; it < 16; ++it) {
    const int k0 = it * 64;
    bf16* PsmC = &Psm[it & 1][0];
    // content scores: K b-frags direct from global (L2-hot)
    const bf16* krow = Kbh + (size_t)(k0 + kk) * 64 + hi * 8;
    const short8 b0 = *(const short8*)(krow);
    const short8 b1 = *(const short8*)(krow + 32);
    f32x4 s = {0.f, 0.f, 0.f, 0.f};
    s = mfma16(aq0, b0, s);
    s = mfma16(aq1, b1, s);
    // + QP[pos] (fp8 LDS gather) + mask, *0.125, exp -> Psm[cur]
#pragma unroll
    for (int j = 0; j < 4; ++j) {
      const int q = hi * 4 + j;
      const size_t go = (size_t)(qg0 + q) * TT + k0 + kk;
      const int p = pos[go];
      const float qp =
          __builtin_amdgcn_cvt_f32_fp8((int)QPsh[q * QP8_S + p], 0);
      float sv = s[j] + qp;
      sv = (sv + maskp[go]) * 0.125f;
      const float pe = __expf(sv);
      lp[j] += pe;
      PsmC[q * PSM_S + kk] = __float2bfloat16(pe);
    }
    __syncthreads();
    // store P tile to global (unnormalized), coalesced via LDS
    {
      const int r = tid >> 4, c = (tid & 15) * 4;
      *(short4v*)(Pws + ((size_t)(qlocal0 + r) * 64 + bh) * TT + k0 + c) =
          *(const short4v*)(PsmC + r * PSM_S + c);
    }
    // PV MFMAs: wave w's d-tile, Vt b-frags direct from global
#pragma unroll
    for (int kc = 0; kc < 2; ++kc) {
      const short8 pa = *(const short8*)(PsmC + l15 * PSM_S + kc * 32 + hi * 8);
      const short8 bv = *(const short8*)(Vtrow + k0 + kc * 32 + hi * 8);
      acc_pv = mfma16(pa, bv, acc_pv);
    }
    // no trailing barrier: next iter writes the other Psm buffer
  }

  // l row-sums: waves hold disjoint k-slices -> sum across lanes then waves
#pragma unroll
  for (int j = 0; j < 4; ++j) {
    float v = lp[j];
    v += __shfl_xor(v, 1);
    v += __shfl_xor(v, 2);
    v += __shfl_xor(v, 4);
    v += __shfl_xor(v, 8);
    if (l15 == 0) lred[w][hi * 4 + j] = v;
  }
  __syncthreads();
  if (tid < 16) {
    const float l = lred[0][tid] + lred[1][tid] + lred[2][tid] + lred[3][tid];
    l_ws[(size_t)bh * TT + qg0 + tid] = l;
  }
  // ctxU scatter: wave w owns d-range [w*16, w*16+16); rows q = hi*4+j
  {
    const int b = bh >> 4, h = bh & 15;
#pragma unroll
    for (int j = 0; j < 4; ++j) {
      const int q = hi * 4 + j;
      ctxU[((size_t)b * TT + qg0 + q) * DM + h * 64 + w * 16 + l15] = acc_pv[j];
    }
  }
}

// ---------------------------------------------------------------------------
// PV gather via MFMA: one block per q. ctxPV = P[64bh x 1024k] @ PVt^T.
// Fuses ctxU add + 1/l normalize + bf16 ctxB write. grid 256/slab, block 256.
// ---------------------------------------------------------------------------
#define PVT_S 72
#define PSH_S 72
__global__ __launch_bounds__(256) void pv_mfma_kernel(
    const bf16* __restrict__ Pws,
    const float* __restrict__ posV,
    const int* __restrict__ pos,
    const float* __restrict__ l_ws,
    const float* __restrict__ ctxU,
    bf16* __restrict__ ctxB,
    int slab) {
  __shared__ __align__(16) bf16 PVt[64 * PVT_S];  // [d][k] transposed
  __shared__ __align__(16) bf16 Psh[64 * PSH_S];  // [bh][k]
  __shared__ unsigned short possh[1024];

  const int qlocal = blockIdx.x;
  const int q = slab * 256 + qlocal;
  const int tid = threadIdx.x;
  const int w = tid >> 6, lane = tid & 63, l15 = lane & 15, hi = lane >> 4;

  for (int i = tid; i < 1024; i += 256)
    possh[i] = (unsigned short)pos[(size_t)q * TT + i];
  __syncthreads();

  f32x4 acc[4] = {{0.f, 0.f, 0.f, 0.f}, {0.f, 0.f, 0.f, 0.f},
                  {0.f, 0.f, 0.f, 0.f}, {0.f, 0.f, 0.f, 0.f}};

  for (int it = 0; it < 16; ++it) {
    const int k0 = it * 64;
    // stage P tile [64 bh][64 k] (coalesced)
    {
      const int r = tid >> 2, c = (tid & 3) * 16;
      const bf16* psrc = Pws + ((size_t)qlocal * 64 + r) * TT + k0 + c;
      *(short8*)(Psh + r * PSH_S + c) = *(const short8*)(psrc);
      *(short8*)(Psh + r * PSH_S + c + 8) = *(const short8*)(psrc + 8);
    }
    // stage gathered posV rows transposed: lane = k-row, wave picks d-chunk.
    {
      const int kr = lane;
      const int dc = w * 16;
      const int p = possh[k0 + kr];
      const float* src = posV + (size_t)p * 64 + dc;
#pragma unroll
      for (int ii = 0; ii < 16; ii += 4) {
        const f32x4 v = *(const f32x4*)(src + ii);
        PVt[(dc + ii + 0) * PVT_S + kr] = __float2bfloat16(v[0]);
        PVt[(dc + ii + 1) * PVT_S + kr] = __float2bfloat16(v[1]);
        PVt[(dc + ii + 2) * PVT_S + kr] = __float2bfloat16(v[2]);
        PVt[(dc + ii + 3) * PVT_S + kr] = __float2bfloat16(v[3]);
      }
    }
    __syncthreads();
#pragma unroll
    for (int kc = 0; kc < 2; ++kc) {
      const short8 a =
          *(const short8*)(Psh + (w * 16 + l15) * PSH_S + kc * 32 + hi * 8);
#pragma unroll
      for (int nt = 0; nt < 4; ++nt) {
        const short8 bv = *(const short8*)(PVt + (nt * 16 + l15) * PVT_S +
                                           kc * 32 + hi * 8);
        acc[nt] = mfma16(a, bv, acc[nt]);
      }
    }
    __syncthreads();
  }

  const int bh0 = w * 16 + hi * 4;
#pragma unroll
  for (int j = 0; j < 4; ++j) {
    const int bh = bh0 + j;
    const int b = bh >> 4, h = bh & 15;
    const float invl = 1.0f / l_ws[(size_t)bh * TT + q];
    const size_t base = ((size_t)b * TT + q) * DM + h * 64;
#pragma unroll
    for (int nt = 0; nt < 4; ++nt) {
      const size_t o = base + nt * 16 + l15;
      ctxB[o] = __float2bfloat16((ctxU[o] + acc[nt][j]) * invl);
    }
  }
}

// ---------------------------------------------------------------------------
// Output projection (MFMA): out[4096][1024] = ctxB @ Wz  (B from WzT)
// ---------------------------------------------------------------------------
__global__ __launch_bounds__(256, 4) void outproj_mfma_kernel(
    const bf16* __restrict__ A,
    const bf16* __restrict__ Bt,
    float* __restrict__ C) {
  const int tid = threadIdx.x;
  const int w = tid >> 6, lane = tid & 63, l15 = lane & 15, hi = lane >> 4;
  const int m0 = blockIdx.y * 64 + w * 16;
  const int n0 = blockIdx.x * 64;
  f32x4 acc[4] = {{0.f, 0.f, 0.f, 0.f}, {0.f, 0.f, 0.f, 0.f},
                  {0.f, 0.f, 0.f, 0.f}, {0.f, 0.f, 0.f, 0.f}};
  for (int kc = 0; kc < 1024; kc += 32) {
    const short8 a =
        *(const short8*)(A + (size_t)(m0 + l15) * 1024 + kc + hi * 8);
#pragma unroll
    for (int nt = 0; nt < 4; ++nt) {
      const short8 b = *(const short8*)(
          Bt + (size_t)(n0 + nt * 16 + l15) * 1024 + kc + hi * 8);
      acc[nt] = mfma16(a, b, acc[nt]);
    }
  }
#pragma unroll
  for (int nt = 0; nt < 4; ++nt)
#pragma unroll
    for (int j = 0; j < 4; ++j)
      C[(size_t)(m0 + hi * 4 + j) * 1024 + n0 + nt * 16 + l15] = acc[nt][j];
}

// ---------------------------------------------------------------------------
extern "C" void kernel_launch(void* const* d_in, const int* in_sizes, int n_in,
                              void* d_out, int out_size, void* d_ws,
                              size_t ws_size, hipStream_t stream) {
  const float* x = (const float*)d_in[0];
  const float* WQ = (const float*)d_in[1];
  const float* WK = (const float*)d_in[2];
  const float* WV = (const float*)d_in[3];
  const float* WZ = (const float*)d_in[4];
  const float* posK = (const float*)d_in[5];
  const float* posV = (const float*)d_in[6];
  const float* maskp = (const float*)d_in[7];
  const int* pos = (const int*)d_in[8];
  float* out = (float*)d_out;

  char* p = (char*)d_ws;
  bf16* Qb = (bf16*)p;        p += (size_t)64 * 1024 * 64 * 2;   // 8 MB
  bf16* Kb = (bf16*)p;        p += (size_t)64 * 1024 * 64 * 2;   // 8 MB
  bf16* Vb = (bf16*)p;        p += (size_t)64 * 1024 * 64 * 2;   // 8 MB
  bf16* Vt = (bf16*)p;        p += (size_t)64 * 64 * 1024 * 2;   // 8 MB
  bf16* posKbf = (bf16*)p;    p += (size_t)2048 * 64 * 2;        // 256 KB
  bf16* WzT = (bf16*)p;       p += (size_t)1024 * 1024 * 2;      // 2 MB
  bf16* Pws = (bf16*)p;       p += (size_t)256 * 64 * 1024 * 2;  // 32 MB
  float* l_ws = (float*)p;    p += (size_t)64 * 1024 * 4;        // 256 KB
  float* ctxU = (float*)p;    p += (size_t)4 * 1024 * 1024 * 4;  // 16 MB
  bf16* ctxB = (bf16*)p;      p += (size_t)4 * 1024 * 1024 * 2;  // 8 MB

  // Aliases (dead-range reuse, safe under stream ordering):
  bf16* xb = (bf16*)ctxU;  // xb dead after qkv; ctxU written later
  bf16* Wt = ctxB;         // Wt dead after qkv; ctxB written later

  xb_kernel<<<2048, 256, 0, stream>>>(x, xb);
  prep_w_kernel<<<dim3(16, 3), 256, 0, stream>>>(WQ, WK, WV, Wt);
  prep_posk_kernel<<<512, 256, 0, stream>>>(posK, posKbf);
  trans_wz_kernel<<<dim3(16, 16), 256, 0, stream>>>(WZ, WzT);
  qkv_mfma_kernel<<<dim3(16, 64), 256, 0, stream>>>(xb, Wt, Qb, Kb, Vb);
  trans_v_kernel<<<dim3(16, 64), 256, 0, stream>>>(Vb, Vt);

  for (int slab = 0; slab < 4; ++slab) {
    score_pv_kernel<<<dim3(16, 64), 256, 0, stream>>>(
        Qb, Kb, posKbf, Vt, maskp, pos, Pws, l_ws, ctxU, slab);
    pv_mfma_kernel<<<256, 256, 0, stream>>>(Pws, posV, pos, l_ws, ctxU, ctxB,
                                            slab);
  }
  outproj_mfma_kernel<<<dim3(16, 64), 256, 0, stream>>>(ctxB, WzT, out);
}

// Round 6
// 419.480 us; speedup vs baseline: 10.9346x; 1.1861x over previous
//
#include <hip/hip_runtime.h>
#include <hip/hip_bf16.h>

#define BB 4
#define TT 1024
#define DM 1024
#define HH 16

typedef __attribute__((ext_vector_type(8))) short short8;
typedef __attribute__((ext_vector_type(4))) short short4v;
typedef __attribute__((ext_vector_type(4))) float f32x4;
typedef __hip_bfloat16 bf16;

__device__ __forceinline__ f32x4 mfma16(short8 a, short8 b, f32x4 c) {
  return __builtin_amdgcn_mfma_f32_16x16x32_bf16(a, b, c, 0, 0, 0);
}

// ---------------------------------------------------------------------------
// x fp32 -> bf16, 8 elems/thread. grid 2048.
// ---------------------------------------------------------------------------
__global__ __launch_bounds__(256) void xb_kernel(
    const float* __restrict__ x, bf16* __restrict__ xb) {
  const size_t i = ((size_t)blockIdx.x * 256 + threadIdx.x) * 8;
  bf16 tmp[8];
#pragma unroll
  for (int j = 0; j < 8; ++j) tmp[j] = __float2bfloat16(x[i + j]);
  *(short8*)(xb + i) = *(const short8*)tmp;
}

// ---------------------------------------------------------------------------
// W_{Q,K,V} fp32 [16][64 d][64 e] -> Wt bf16 [3][16][64 e][64 d] (transposed)
// grid (16 h, 3 m)
// ---------------------------------------------------------------------------
__global__ __launch_bounds__(256) void prep_w_kernel(
    const float* __restrict__ WQ, const float* __restrict__ WK,
    const float* __restrict__ WV, bf16* __restrict__ Wt) {
  __shared__ bf16 tl[64][72];
  const int h = blockIdx.x, m = blockIdx.y;
  const float* W = (m == 0 ? WQ : (m == 1 ? WK : WV)) + h * 4096;
  const int tid = threadIdx.x;
  const int r = tid >> 2, c = (tid & 3) * 16;
#pragma unroll
  for (int i = 0; i < 16; ++i)
    tl[r][c + i] = __float2bfloat16(W[r * 64 + c + i]);  // tl[d][e]
  __syncthreads();
  bf16* o = Wt + ((size_t)(m * 16 + h) * 64 + r) * 64 + c;  // [e=r][d=c..]
#pragma unroll
  for (int i = 0; i < 16; ++i) o[i] = tl[c + i][r];
}

// ---------------------------------------------------------------------------
// prep: posK fp32 [2047][64] -> bf16 [2048][64] (row 2047 zeroed)
// ---------------------------------------------------------------------------
__global__ __launch_bounds__(256) void prep_posk_kernel(
    const float* __restrict__ posK, bf16* __restrict__ posKbf) {
  const int idx = blockIdx.x * 256 + threadIdx.x;
  const int p = idx >> 6, d = idx & 63;
  const float v = (p < 2047) ? posK[(size_t)p * 64 + d] : 0.f;
  posKbf[idx] = __float2bfloat16(v);
}

// ---------------------------------------------------------------------------
// prep: WzT bf16 [n][k] = Wz fp32 [k][n]
// ---------------------------------------------------------------------------
__global__ __launch_bounds__(256) void trans_wz_kernel(
    const float* __restrict__ Wz, bf16* __restrict__ WzT) {
  __shared__ bf16 tile[64][72];
  const int k0 = blockIdx.y * 64, n0 = blockIdx.x * 64;
  const int tid = threadIdx.x;
  const int r = tid >> 2, c = (tid & 3) * 16;
  const float* s = Wz + (size_t)(k0 + r) * 1024 + n0 + c;
#pragma unroll
  for (int i = 0; i < 16; ++i) tile[r][c + i] = __float2bfloat16(s[i]);
  __syncthreads();
  const int n = tid >> 2;
  bf16* o = WzT + (size_t)(n0 + n) * 1024 + k0 + c;
#pragma unroll
  for (int i = 0; i < 16; ++i) o[i] = tile[c + i][n];
}

// ---------------------------------------------------------------------------
// transpose V: [bh][1024][64] bf16 -> Vt [bh][64][1024] bf16
// ---------------------------------------------------------------------------
__global__ __launch_bounds__(256) void trans_v_kernel(
    const bf16* __restrict__ src, bf16* __restrict__ dst) {
  __shared__ bf16 tile[64][72];
  const int bh = blockIdx.y, t0 = blockIdx.x * 64;
  const int tid = threadIdx.x;
  const int r = tid >> 2, c = (tid & 3) * 16;
  const bf16* s = src + ((size_t)bh * TT + t0 + r) * 64 + c;
  *(short8*)(&tile[r][c]) = *(const short8*)(s);
  *(short8*)(&tile[r][c + 8]) = *(const short8*)(s + 8);
  __syncthreads();
  const int d = tid >> 2;
  bf16* o = dst + ((size_t)bh * 64 + d) * TT + t0 + c;
#pragma unroll
  for (int i = 0; i < 16; ++i) o[i] = tile[c + i][d];
}

// ---------------------------------------------------------------------------
// QKV projection via MFMA. grid (16 ttiles, 64 bh), block 256 (4 waves).
// ---------------------------------------------------------------------------
__global__ __launch_bounds__(256) void qkv_mfma_kernel(
    const bf16* __restrict__ xb, const bf16* __restrict__ Wt,
    bf16* __restrict__ Qg, bf16* __restrict__ Kg, bf16* __restrict__ Vg) {
  __shared__ __align__(16) bf16 xs[64 * 72];
  const int bh = blockIdx.y;
  const int b = bh >> 4, h = bh & 15;
  const int t0 = blockIdx.x * 64;
  const int tid = threadIdx.x;
  const int w = tid >> 6, lane = tid & 63, l15 = lane & 15, hi = lane >> 4;

  {
    const int r = tid >> 2, c = (tid & 3) * 16;
    const bf16* src = xb + ((size_t)b * TT + t0 + r) * DM + h * 64 + c;
    *(short8*)(xs + r * 72 + c) = *(const short8*)(src);
    *(short8*)(xs + r * 72 + c + 8) = *(const short8*)(src + 8);
  }
  __syncthreads();

  f32x4 aQ[4] = {{0.f, 0.f, 0.f, 0.f}, {0.f, 0.f, 0.f, 0.f},
                 {0.f, 0.f, 0.f, 0.f}, {0.f, 0.f, 0.f, 0.f}};
  f32x4 aK[4] = {{0.f, 0.f, 0.f, 0.f}, {0.f, 0.f, 0.f, 0.f},
                 {0.f, 0.f, 0.f, 0.f}, {0.f, 0.f, 0.f, 0.f}};
  f32x4 aV[4] = {{0.f, 0.f, 0.f, 0.f}, {0.f, 0.f, 0.f, 0.f},
                 {0.f, 0.f, 0.f, 0.f}, {0.f, 0.f, 0.f, 0.f}};
  const bf16* WtQ = Wt + (size_t)h * 4096;
  const bf16* WtK = Wt + (size_t)(16 + h) * 4096;
  const bf16* WtV = Wt + (size_t)(32 + h) * 4096;
#pragma unroll
  for (int kc = 0; kc < 2; ++kc) {
    const short8 a =
        *(const short8*)(xs + (w * 16 + l15) * 72 + kc * 32 + hi * 8);
#pragma unroll
    for (int nt = 0; nt < 4; ++nt) {
      const size_t wo = (size_t)(nt * 16 + l15) * 64 + kc * 32 + hi * 8;
      aQ[nt] = mfma16(a, *(const short8*)(WtQ + wo), aQ[nt]);
      aK[nt] = mfma16(a, *(const short8*)(WtK + wo), aK[nt]);
      aV[nt] = mfma16(a, *(const short8*)(WtV + wo), aV[nt]);
    }
  }
  const int t = t0 + w * 16 + hi * 4;
#pragma unroll
  for (int nt = 0; nt < 4; ++nt) {
#pragma unroll
    for (int j = 0; j < 4; ++j) {
      const size_t o = ((size_t)bh * TT + t + j) * 64 + nt * 16 + l15;
      Qg[o] = __float2bfloat16(aQ[nt][j]);
      Kg[o] = __float2bfloat16(aK[nt][j]);
      Vg[o] = __float2bfloat16(aV[nt][j]);
    }
  }
}

// ---------------------------------------------------------------------------
// Fused score kernel (unchanged from round 5).
// ---------------------------------------------------------------------------
#define QP8_S 2052
#define PSM_S 72

__global__ __launch_bounds__(256, 4) void score_pv_kernel(
    const bf16* __restrict__ Qb,
    const bf16* __restrict__ Kb,
    const bf16* __restrict__ posKbf,
    const bf16* __restrict__ Vt,
    const float* __restrict__ maskp,
    const int* __restrict__ pos,
    bf16* __restrict__ Pws,        // [256 qlocal][64 bh][1024 k]
    float* __restrict__ l_ws,      // [64 bh][1024 q]
    float* __restrict__ ctxU,      // [b][t][1024] fp32 unnormalized
    int slab) {
  __shared__ __align__(16) unsigned char QPsh[16 * QP8_S];  // 32832 B
  __shared__ __align__(16) bf16 Psm[2][16 * PSM_S];         // 4608 B
  __shared__ float lred[4][16];                             // 256 B

  const int bh = blockIdx.y;
  const int qt = blockIdx.x;
  const int qlocal0 = qt * 16;
  const int qg0 = slab * 256 + qlocal0;
  const int tid = threadIdx.x;
  const int w = tid >> 6;
  const int lane = tid & 63;
  const int l15 = lane & 15;
  const int hi = lane >> 4;

  const bf16* Qrow = Qb + ((size_t)bh * TT + qg0 + l15) * 64 + hi * 8;
  const short8 aq0 = *(const short8*)(Qrow);
  const short8 aq1 = *(const short8*)(Qrow + 32);

  // ---- QP phase: wave w covers p-tiles w*32 .. w*32+31; store fp8
  for (int i = 0; i < 32; ++i) {
    const int pt = w * 32 + i;
    const bf16* Kp = posKbf + ((size_t)(pt * 16 + l15)) * 64 + hi * 8;
    const short8 b0 = *(const short8*)(Kp);
    const short8 b1 = *(const short8*)(Kp + 32);
    f32x4 acc = {0.f, 0.f, 0.f, 0.f};
    acc = mfma16(aq0, b0, acc);
    acc = mfma16(aq1, b1, acc);
    const int p01 = __builtin_amdgcn_cvt_pk_fp8_f32(acc[0], acc[1], 0, false);
    const int p23 = __builtin_amdgcn_cvt_pk_fp8_f32(acc[2], acc[3], 0, false);
    const int off = pt * 16 + l15;
    QPsh[(hi * 4 + 0) * QP8_S + off] = (unsigned char)(p01 & 0xff);
    QPsh[(hi * 4 + 1) * QP8_S + off] = (unsigned char)((p01 >> 8) & 0xff);
    QPsh[(hi * 4 + 2) * QP8_S + off] = (unsigned char)(p23 & 0xff);
    QPsh[(hi * 4 + 3) * QP8_S + off] = (unsigned char)((p23 >> 8) & 0xff);
  }
  __syncthreads();

  f32x4 acc_pv = {0.f, 0.f, 0.f, 0.f};
  float lp[4] = {0.f, 0.f, 0.f, 0.f};
  const int kk = w * 16 + l15;
  const bf16* Kbh = Kb + (size_t)bh * TT * 64;
  const bf16* Vtrow = Vt + ((size_t)bh * 64 + w * 16 + l15) * TT;

  for (int it = 0; it < 16; ++it) {
    const int k0 = it * 64;
    bf16* PsmC = &Psm[it & 1][0];
    const bf16* krow = Kbh + (size_t)(k0 + kk) * 64 + hi * 8;
    const short8 b0 = *(const short8*)(krow);
    const short8 b1 = *(const short8*)(krow + 32);
    f32x4 s = {0.f, 0.f, 0.f, 0.f};
    s = mfma16(aq0, b0, s);
    s = mfma16(aq1, b1, s);
#pragma unroll
    for (int j = 0; j < 4; ++j) {
      const int q = hi * 4 + j;
      const size_t go = (size_t)(qg0 + q) * TT + k0 + kk;
      const int p = pos[go];
      const float qp =
          __builtin_amdgcn_cvt_f32_fp8((int)QPsh[q * QP8_S + p], 0);
      float sv = s[j] + qp;
      sv = (sv + maskp[go]) * 0.125f;
      const float pe = __expf(sv);
      lp[j] += pe;
      PsmC[q * PSM_S + kk] = __float2bfloat16(pe);
    }
    __syncthreads();
    {
      const int r = tid >> 4, c = (tid & 15) * 4;
      *(short4v*)(Pws + ((size_t)(qlocal0 + r) * 64 + bh) * TT + k0 + c) =
          *(const short4v*)(PsmC + r * PSM_S + c);
    }
#pragma unroll
    for (int kc = 0; kc < 2; ++kc) {
      const short8 pa = *(const short8*)(PsmC + l15 * PSM_S + kc * 32 + hi * 8);
      const short8 bv = *(const short8*)(Vtrow + k0 + kc * 32 + hi * 8);
      acc_pv = mfma16(pa, bv, acc_pv);
    }
  }

#pragma unroll
  for (int j = 0; j < 4; ++j) {
    float v = lp[j];
    v += __shfl_xor(v, 1);
    v += __shfl_xor(v, 2);
    v += __shfl_xor(v, 4);
    v += __shfl_xor(v, 8);
    if (l15 == 0) lred[w][hi * 4 + j] = v;
  }
  __syncthreads();
  if (tid < 16) {
    const float l = lred[0][tid] + lred[1][tid] + lred[2][tid] + lred[3][tid];
    l_ws[(size_t)bh * TT + qg0 + tid] = l;
  }
  {
    const int b = bh >> 4, h = bh & 15;
#pragma unroll
    for (int j = 0; j < 4; ++j) {
      const int q = hi * 4 + j;
      ctxU[((size_t)b * TT + qg0 + q) * DM + h * 64 + w * 16 + l15] = acc_pv[j];
    }
  }
}

// ---------------------------------------------------------------------------
// PV partial kernel (k-split x4): grid (256 q, 4 ks), block 256.
// Each block: k-range [ks*256, ks*256+256); P a-frags direct from global;
// gathered posV^T double-buffered in LDS (1 barrier/iter).
// Writes fp32 partials PP[ks][qlocal][bh][d].
// ---------------------------------------------------------------------------
#define PVT_S 72
__global__ __launch_bounds__(256) void pv_part_kernel(
    const bf16* __restrict__ Pws,
    const float* __restrict__ posV,
    const int* __restrict__ pos,
    float* __restrict__ PP,   // [4][256][64][64] fp32
    int slab) {
  __shared__ __align__(16) bf16 PVt[2][64 * PVT_S];
  __shared__ unsigned short possh[256];

  const int qlocal = blockIdx.x;
  const int q = slab * 256 + qlocal;
  const int ks = blockIdx.y;
  const int kbase = ks * 256;
  const int tid = threadIdx.x;
  const int w = tid >> 6, lane = tid & 63, l15 = lane & 15, hi = lane >> 4;

  possh[tid] = (unsigned short)pos[(size_t)q * TT + kbase + tid];
  __syncthreads();

  f32x4 acc[4] = {{0.f, 0.f, 0.f, 0.f}, {0.f, 0.f, 0.f, 0.f},
                  {0.f, 0.f, 0.f, 0.f}, {0.f, 0.f, 0.f, 0.f}};
  const bf16* Prow = Pws + ((size_t)qlocal * 64 + w * 16 + l15) * TT;

  for (int it = 0; it < 4; ++it) {
    const int k0 = kbase + it * 64;
    bf16* pvt = &PVt[it & 1][0];
    // stage gathered posV rows transposed: lane = k-row, wave picks d-chunk
    {
      const int kr = lane;
      const int dc = w * 16;
      const int p = possh[it * 64 + kr];
      const float* src = posV + (size_t)p * 64 + dc;
#pragma unroll
      for (int ii = 0; ii < 16; ii += 4) {
        const f32x4 v = *(const f32x4*)(src + ii);
        pvt[(dc + ii + 0) * PVT_S + kr] = __float2bfloat16(v[0]);
        pvt[(dc + ii + 1) * PVT_S + kr] = __float2bfloat16(v[1]);
        pvt[(dc + ii + 2) * PVT_S + kr] = __float2bfloat16(v[2]);
        pvt[(dc + ii + 3) * PVT_S + kr] = __float2bfloat16(v[3]);
      }
    }
    __syncthreads();
#pragma unroll
    for (int kc = 0; kc < 2; ++kc) {
      const short8 a = *(const short8*)(Prow + k0 + kc * 32 + hi * 8);
#pragma unroll
      for (int nt = 0; nt < 4; ++nt) {
        const short8 bv =
            *(const short8*)(pvt + (nt * 16 + l15) * PVT_S + kc * 32 + hi * 8);
        acc[nt] = mfma16(a, bv, acc[nt]);
      }
    }
    // next iter stages the other PVt buffer; barrier at top of its stage
  }

  const int bh0 = w * 16 + hi * 4;
#pragma unroll
  for (int j = 0; j < 4; ++j) {
    const int bh = bh0 + j;
    float* o = PP + (((size_t)ks * 256 + qlocal) * 64 + bh) * 64;
#pragma unroll
    for (int nt = 0; nt < 4; ++nt) o[nt * 16 + l15] = acc[nt][j];
  }
}

// ---------------------------------------------------------------------------
// Normalize: ctxB = (ctxU + sum_ks PP) / l. grid 1024, block 256, f32x4/thread.
// ---------------------------------------------------------------------------
__global__ __launch_bounds__(256) void norm_kernel(
    const float* __restrict__ PP,
    const float* __restrict__ ctxU,
    const float* __restrict__ l_ws,
    bf16* __restrict__ ctxB,
    int slab) {
  const int i4 = blockIdx.x * 256 + threadIdx.x;  // 0..262143
  const int e0 = i4 * 4;
  const int dm = e0 & 1023;
  const int qlocal = (e0 >> 10) & 255;
  const int b = e0 >> 18;
  const int h = dm >> 6, d0 = dm & 63;
  const int bh = b * 16 + h;
  const int q = slab * 256 + qlocal;

  f32x4 v = *(const f32x4*)(ctxU + ((size_t)b * TT + q) * DM + dm);
#pragma unroll
  for (int ks = 0; ks < 4; ++ks)
    v += *(const f32x4*)(PP + (((size_t)ks * 256 + qlocal) * 64 + bh) * 64 + d0);
  const float invl = 1.0f / l_ws[(size_t)bh * TT + q];
  bf16 o[4];
#pragma unroll
  for (int j = 0; j < 4; ++j) o[j] = __float2bfloat16(v[j] * invl);
  *(short4v*)(ctxB + ((size_t)b * TT + q) * DM + dm) = *(const short4v*)o;
}

// ---------------------------------------------------------------------------
// Output projection v2: 128x128 LDS-tiled MFMA GEMM, BK=64, 4 waves (2x2).
// grid (8 nblk, 32 mblk), block 256.
// ---------------------------------------------------------------------------
__global__ __launch_bounds__(256) void outproj_mfma_kernel(
    const bf16* __restrict__ A,   // [4096][1024] bf16
    const bf16* __restrict__ Bt,  // [1024 n][1024 k] bf16
    float* __restrict__ C) {
  __shared__ __align__(16) bf16 As[128 * 72];
  __shared__ __align__(16) bf16 Bs[128 * 72];
  const int n0 = blockIdx.x * 128;
  const int m0 = blockIdx.y * 128;
  const int tid = threadIdx.x;
  const int w = tid >> 6, lane = tid & 63, l15 = lane & 15, hi = lane >> 4;
  const int wm = w >> 1, wn = w & 1;

  f32x4 acc[4][4];
#pragma unroll
  for (int i = 0; i < 4; ++i)
#pragma unroll
    for (int j = 0; j < 4; ++j) acc[i][j] = (f32x4){0.f, 0.f, 0.f, 0.f};

  const int sr = tid >> 1, sc = (tid & 1) * 32;
  for (int k0 = 0; k0 < 1024; k0 += 64) {
    __syncthreads();  // previous-iter reads complete before overwrite
    {
      const bf16* as = A + (size_t)(m0 + sr) * 1024 + k0 + sc;
      const bf16* bs = Bt + (size_t)(n0 + sr) * 1024 + k0 + sc;
#pragma unroll
      for (int ii = 0; ii < 32; ii += 8) {
        *(short8*)(As + sr * 72 + sc + ii) = *(const short8*)(as + ii);
        *(short8*)(Bs + sr * 72 + sc + ii) = *(const short8*)(bs + ii);
      }
    }
    __syncthreads();
#pragma unroll
    for (int kc = 0; kc < 2; ++kc) {
      short8 a[4], b[4];
#pragma unroll
      for (int i = 0; i < 4; ++i)
        a[i] = *(const short8*)(As + (wm * 64 + i * 16 + l15) * 72 + kc * 32 +
                                hi * 8);
#pragma unroll
      for (int j = 0; j < 4; ++j)
        b[j] = *(const short8*)(Bs + (wn * 64 + j * 16 + l15) * 72 + kc * 32 +
                                hi * 8);
#pragma unroll
      for (int i = 0; i < 4; ++i)
#pragma unroll
        for (int j = 0; j < 4; ++j) acc[i][j] = mfma16(a[i], b[j], acc[i][j]);
    }
  }
#pragma unroll
  for (int i = 0; i < 4; ++i) {
#pragma unroll
    for (int jj = 0; jj < 4; ++jj) {
      const size_t row = (size_t)(m0 + wm * 64 + i * 16 + hi * 4 + jj) * 1024;
#pragma unroll
      for (int j = 0; j < 4; ++j)
        C[row + n0 + wn * 64 + j * 16 + l15] = acc[i][j][jj];
    }
  }
}

// ---------------------------------------------------------------------------
extern "C" void kernel_launch(void* const* d_in, const int* in_sizes, int n_in,
                              void* d_out, int out_size, void* d_ws,
                              size_t ws_size, hipStream_t stream) {
  const float* x = (const float*)d_in[0];
  const float* WQ = (const float*)d_in[1];
  const float* WK = (const float*)d_in[2];
  const float* WV = (const float*)d_in[3];
  const float* WZ = (const float*)d_in[4];
  const float* posK = (const float*)d_in[5];
  const float* posV = (const float*)d_in[6];
  const float* maskp = (const float*)d_in[7];
  const int* pos = (const int*)d_in[8];
  float* out = (float*)d_out;

  char* p = (char*)d_ws;
  bf16* Qb = (bf16*)p;        p += (size_t)64 * 1024 * 64 * 2;   // 8 MB
  bf16* Kb = (bf16*)p;        p += (size_t)64 * 1024 * 64 * 2;   // 8 MB
  bf16* Vb = (bf16*)p;        p += (size_t)64 * 1024 * 64 * 2;   // 8 MB
  bf16* Vt = (bf16*)p;        p += (size_t)64 * 64 * 1024 * 2;   // 8 MB
  bf16* posKbf = (bf16*)p;    p += (size_t)2048 * 64 * 2;        // 256 KB
  bf16* WzT = (bf16*)p;       p += (size_t)1024 * 1024 * 2;      // 2 MB
  bf16* Pws = (bf16*)p;       p += (size_t)256 * 64 * 1024 * 2;  // 32 MB
  float* l_ws = (float*)p;    p += (size_t)64 * 1024 * 4;        // 256 KB
  float* ctxU = (float*)p;    p += (size_t)4 * 1024 * 1024 * 4;  // 16 MB
  bf16* ctxB = (bf16*)p;      p += (size_t)4 * 1024 * 1024 * 2;  // 8 MB
  float* PP = (float*)p;      p += (size_t)4 * 256 * 64 * 64 * 4; // 16 MB

  // Aliases (dead-range reuse, safe under stream ordering):
  bf16* xb = (bf16*)ctxU;  // xb dead after qkv; ctxU written later
  bf16* Wt = ctxB;         // Wt dead after qkv; ctxB written later

  xb_kernel<<<2048, 256, 0, stream>>>(x, xb);
  prep_w_kernel<<<dim3(16, 3), 256, 0, stream>>>(WQ, WK, WV, Wt);
  prep_posk_kernel<<<512, 256, 0, stream>>>(posK, posKbf);
  trans_wz_kernel<<<dim3(16, 16), 256, 0, stream>>>(WZ, WzT);
  qkv_mfma_kernel<<<dim3(16, 64), 256, 0, stream>>>(xb, Wt, Qb, Kb, Vb);
  trans_v_kernel<<<dim3(16, 64), 256, 0, stream>>>(Vb, Vt);

  for (int slab = 0; slab < 4; ++slab) {
    score_pv_kernel<<<dim3(16, 64), 256, 0, stream>>>(
        Qb, Kb, posKbf, Vt, maskp, pos, Pws, l_ws, ctxU, slab);
    pv_part_kernel<<<dim3(256, 4), 256, 0, stream>>>(Pws, posV, pos, PP, slab);
    norm_kernel<<<1024, 256, 0, stream>>>(PP, ctxU, l_ws, ctxB, slab);
  }
  outproj_mfma_kernel<<<dim3(8, 32), 256, 0, stream>>>(ctxB, WzT, out);
}